// Round 3
// baseline (295.512 us; speedup 1.0000x reference)
//
#include <hip/hip_runtime.h>
#include <hip/hip_bf16.h>

// Problem dims (fixed by reference)
#define BB 8
#define NN 2048
#define DD 256
#define MM (BB * NN)   // 16384 rows

typedef __attribute__((ext_vector_type(8))) short bf16x8_t;  // 8 bf16 = 4 VGPRs
typedef __attribute__((ext_vector_type(4))) float f32x4_t;

// ---------------------------------------------------------------------------
// Kernel A: h = x @ W^T + b. fp32 inputs, converted to bf16 at LDS staging,
// bf16 MFMA w/ fp32 accumulate, h written as bf16 (workspace).
// grid (M/64, 256/64), block 256 (4 waves).
// ---------------------------------------------------------------------------
__global__ __launch_bounds__(256) void gemm_h(
    const float* __restrict__ x,     // [M,256] fp32
    const float* __restrict__ Wt,    // [256,256] fp32 row-major [out,in] (B^T form)
    const float* __restrict__ bias,  // [256] fp32
    __hip_bfloat16* __restrict__ h)  // [M,256] bf16
{
    __shared__ __hip_bfloat16 As[64][72];
    __shared__ __hip_bfloat16 Bs[64][72];

    const int tid  = threadIdx.x;
    const int r    = tid >> 2;          // 0..63 staging row
    const int cs   = (tid & 3) * 16;    // k-segment 0/16/32/48
    const int w    = tid >> 6;          // wave 0..3
    const int lane = tid & 63;
    const int m16  = lane & 15;
    const int quad = lane >> 4;
    const long rowBase = (long)blockIdx.x * 64;
    const int  colBase = blockIdx.y * 64;

    f32x4_t acc[4];
#pragma unroll
    for (int c = 0; c < 4; c++) acc[c] = (f32x4_t){0.f, 0.f, 0.f, 0.f};

    for (int k0 = 0; k0 < 256; k0 += 64) {
        const float4* ag = (const float4*)(x  + (rowBase + r) * 256 + k0 + cs);
        const float4* bg = (const float4*)(Wt + (long)(colBase + r) * 256 + k0 + cs);
        float4 av[4], bv[4];
#pragma unroll
        for (int q = 0; q < 4; q++) { av[q] = ag[q]; bv[q] = bg[q]; }

        __align__(16) __hip_bfloat16 ta[16], tb[16];
#pragma unroll
        for (int q = 0; q < 4; q++) {
            ta[q * 4 + 0] = __float2bfloat16(av[q].x);
            ta[q * 4 + 1] = __float2bfloat16(av[q].y);
            ta[q * 4 + 2] = __float2bfloat16(av[q].z);
            ta[q * 4 + 3] = __float2bfloat16(av[q].w);
            tb[q * 4 + 0] = __float2bfloat16(bv[q].x);
            tb[q * 4 + 1] = __float2bfloat16(bv[q].y);
            tb[q * 4 + 2] = __float2bfloat16(bv[q].z);
            tb[q * 4 + 3] = __float2bfloat16(bv[q].w);
        }

        __syncthreads();
        *(uint4*)&As[r][cs]     = *(uint4*)&ta[0];
        *(uint4*)&As[r][cs + 8] = *(uint4*)&ta[8];
        *(uint4*)&Bs[r][cs]     = *(uint4*)&tb[0];
        *(uint4*)&Bs[r][cs + 8] = *(uint4*)&tb[8];
        __syncthreads();

#pragma unroll
        for (int kk = 0; kk < 64; kk += 32) {
            bf16x8_t af = *(const bf16x8_t*)&As[w * 16 + m16][kk + quad * 8];
#pragma unroll
            for (int c = 0; c < 4; c++) {
                bf16x8_t bf = *(const bf16x8_t*)&Bs[c * 16 + m16][kk + quad * 8];
                acc[c] = __builtin_amdgcn_mfma_f32_16x16x32_bf16(af, bf, acc[c], 0, 0, 0);
            }
        }
    }

    // Epilogue: C/D layout col = lane&15 (N side), row = quad*4 + reg (M side)
#pragma unroll
    for (int c = 0; c < 4; c++) {
        const int col = colBase + c * 16 + m16;
        const float bv = bias[col];
#pragma unroll
        for (int reg = 0; reg < 4; reg++) {
            const long row = rowBase + w * 16 + quad * 4 + reg;
            h[row * 256 + col] = __float2bfloat16(acc[c][reg] + bv);
        }
    }
}

// ---------------------------------------------------------------------------
// Kernel B: s1 = h@a1, s2 = h@a2 per row (fp32). One wave per row.
// ---------------------------------------------------------------------------
struct __attribute__((aligned(8))) bf4 { __hip_bfloat16 v[4]; };

__global__ __launch_bounds__(256) void s_kernel(
    const __hip_bfloat16* __restrict__ h,
    const float* __restrict__ a1,
    const float* __restrict__ a2,
    float* __restrict__ s1, float* __restrict__ s2)
{
    const int w = threadIdx.x >> 6;
    const int lane = threadIdx.x & 63;
    const long row = (long)blockIdx.x * 4 + w;

    bf4 hv = *(const bf4*)(h + row * 256 + lane * 4);
    float4 A1 = *(const float4*)(a1 + lane * 4);
    float4 A2 = *(const float4*)(a2 + lane * 4);
    const float h0 = __bfloat162float(hv.v[0]), h1 = __bfloat162float(hv.v[1]);
    const float h2 = __bfloat162float(hv.v[2]), h3 = __bfloat162float(hv.v[3]);
    float p1 = h0 * A1.x + h1 * A1.y + h2 * A1.z + h3 * A1.w;
    float p2 = h0 * A2.x + h1 * A2.y + h2 * A2.z + h3 * A2.w;
#pragma unroll
    for (int off = 32; off; off >>= 1) {
        p1 += __shfl_down(p1, off);
        p2 += __shfl_down(p2, off);
    }
    if (lane == 0) { s1[row] = p1; s2[row] = p2; }
}

// ---------------------------------------------------------------------------
// Kernel C: sparse attention aggregate. One block per TWO (b,i) rows.
// Half-block (128 threads) per row; each thread owns 2 output channels
// (one dword of bf16 h per gathered neighbor). b = blk&7 for XCD locality.
// ---------------------------------------------------------------------------
__global__ __launch_bounds__(256) void attn_agg(
    const float* __restrict__ adj,
    const float* __restrict__ mask,
    const __hip_bfloat16* __restrict__ h,
    const float* __restrict__ s1,
    const float* __restrict__ s2,
    const float* __restrict__ attb_p,
    float* __restrict__ out)
{
    __shared__ unsigned short s_j[2][2048];
    __shared__ float s_w[2][2048];
    __shared__ int   s_cnt[2];
    __shared__ float s_red[2][2];
    __shared__ float s_inv[2];

    const int tid  = threadIdx.x;
    const int half = tid >> 7;        // which row of the pair
    const int t    = tid & 127;       // lane within half-block
    const int b    = blockIdx.x & 7;
    const int i    = ((blockIdx.x >> 3) << 1) + half;
    const long row = (long)b * NN + i;
    const long mbase = (long)b * NN;

    const float mask_i = mask[row];
    const bool  valid  = (mask_i != 0.f);

    if (t == 0) s_cnt[half] = 0;
    __syncthreads();

    const float si = s1[row] + attb_p[0];

    // ---- scan: 2048 adj entries per row, 16 per thread, coalesced float4 ----
    const float4* arow = (const float4*)(adj + row * NN);
    float lsum = 0.f;
#pragma unroll
    for (int l = 0; l < 4; l++) {
        float4 A = arow[l * 128 + t];       // consecutive lanes -> consecutive 16B
        const int jb = l * 512 + t * 4;
        float av[4] = {A.x, A.y, A.z, A.w};
#pragma unroll
        for (int e = 0; e < 4; e++) {
            if (valid && av[e] != 0.f) {
                const int j = jb + e;
                const float mj = mask[mbase + j];
                if (mj != 0.f) {
                    const float z = si + s2[mbase + j];
                    const float wgt = av[e] * mj / (1.f + __expf(-z));
                    const int pos = atomicAdd(&s_cnt[half], 1);
                    s_j[half][pos] = (unsigned short)j;
                    s_w[half][pos] = wgt;
                    lsum += wgt;
                }
            }
        }
    }

    // ---- denominator: wave reduce, then 2 waves per half via LDS ----
#pragma unroll
    for (int off = 32; off; off >>= 1) lsum += __shfl_down(lsum, off);
    const int lane = tid & 63;
    if (lane == 0) s_red[half][(tid >> 6) & 1] = lsum;
    __syncthreads();
    if (t == 0) s_inv[half] = 1.f / (s_red[half][0] + s_red[half][1] + 1e-8f);
    __syncthreads();

    // ---- gather: thread owns channels {2t, 2t+1}; one dword per neighbor ----
    const int cnt = s_cnt[half];
    const float inv = s_inv[half];
    const unsigned int* h2 = (const unsigned int*)h;       // bf16 pair per uint
    const unsigned int rbase = (unsigned int)(mbase)*128u + (unsigned int)t;
    float accx = 0.f, accy = 0.f;
    int k = 0;
    for (; k + 4 <= cnt; k += 4) {
        ushort4 j4 = *(const ushort4*)&s_j[half][k];
        float4  w4 = *(const float4*)&s_w[half][k];
        unsigned int u0 = h2[rbase + (unsigned int)j4.x * 128u];
        unsigned int u1 = h2[rbase + (unsigned int)j4.y * 128u];
        unsigned int u2 = h2[rbase + (unsigned int)j4.z * 128u];
        unsigned int u3 = h2[rbase + (unsigned int)j4.w * 128u];
        accx += w4.x * __uint_as_float(u0 << 16);
        accy += w4.x * __uint_as_float(u0 & 0xffff0000u);
        accx += w4.y * __uint_as_float(u1 << 16);
        accy += w4.y * __uint_as_float(u1 & 0xffff0000u);
        accx += w4.z * __uint_as_float(u2 << 16);
        accy += w4.z * __uint_as_float(u2 & 0xffff0000u);
        accx += w4.w * __uint_as_float(u3 << 16);
        accy += w4.w * __uint_as_float(u3 & 0xffff0000u);
    }
    for (; k < cnt; k++) {
        const unsigned int jj = s_j[half][k];
        const float wk = s_w[half][k];
        unsigned int u = h2[rbase + jj * 128u];
        accx += wk * __uint_as_float(u << 16);
        accy += wk * __uint_as_float(u & 0xffff0000u);
    }

    float2* o2 = (float2*)(out + row * 256);
    o2[t] = make_float2(accx * inv, accy * inv);   // cnt==0 or invalid -> 0
}

// ---------------------------------------------------------------------------
extern "C" void kernel_launch(void* const* d_in, const int* in_sizes, int n_in,
                              void* d_out, int out_size, void* d_ws, size_t ws_size,
                              hipStream_t stream) {
    const float* x    = (const float*)d_in[0];
    const float* adj  = (const float*)d_in[1];
    const float* mask = (const float*)d_in[2];
    const float* W    = (const float*)d_in[3];
    const float* bias = (const float*)d_in[4];
    const float* a1   = (const float*)d_in[5];
    const float* a2   = (const float*)d_in[6];
    const float* attb = (const float*)d_in[7];
    float* out = (float*)d_out;

    // workspace layout: h bf16 [16384*256] (8 MB) | s1 fp32 [16384] | s2 fp32 [16384]
    __hip_bfloat16* h = (__hip_bfloat16*)d_ws;
    float* s1 = (float*)((char*)d_ws + (size_t)MM * DD * 2);
    float* s2 = s1 + MM;

    gemm_h<<<dim3(MM / 64, DD / 64), 256, 0, stream>>>(x, W, bias, h);
    s_kernel<<<MM / 4, 256, 0, stream>>>(h, a1, a2, s1, s2);
    attn_agg<<<MM / 2, 256, 0, stream>>>(adj, mask, h, s1, s2, attb, out);
}

// Round 4
// 266.520 us; speedup vs baseline: 1.1088x; 1.1088x over previous
//
#include <hip/hip_runtime.h>
#include <hip/hip_bf16.h>

// Problem dims (fixed by reference)
#define BB 8
#define NN 2048
#define DD 256
#define MM (BB * NN)   // 16384 rows

typedef __attribute__((ext_vector_type(8))) short bf16x8_t;  // 8 bf16 = 4 VGPRs
typedef __attribute__((ext_vector_type(4))) float f32x4_t;

// ---------------------------------------------------------------------------
// Kernel A: h = x @ W^T + b. fp32 inputs, converted to bf16 at LDS staging,
// bf16 MFMA w/ fp32 accumulate, h written as bf16 (workspace).
// grid (M/64, 256/64), block 256 (4 waves).
// ---------------------------------------------------------------------------
__global__ __launch_bounds__(256) void gemm_h(
    const float* __restrict__ x,     // [M,256] fp32
    const float* __restrict__ Wt,    // [256,256] fp32 row-major [out,in] (B^T form)
    const float* __restrict__ bias,  // [256] fp32
    __hip_bfloat16* __restrict__ h)  // [M,256] bf16
{
    __shared__ __hip_bfloat16 As[64][72];
    __shared__ __hip_bfloat16 Bs[64][72];

    const int tid  = threadIdx.x;
    const int r    = tid >> 2;          // 0..63 staging row
    const int cs   = (tid & 3) * 16;    // k-segment 0/16/32/48
    const int w    = tid >> 6;          // wave 0..3
    const int lane = tid & 63;
    const int m16  = lane & 15;
    const int quad = lane >> 4;
    const long rowBase = (long)blockIdx.x * 64;
    const int  colBase = blockIdx.y * 64;

    f32x4_t acc[4];
#pragma unroll
    for (int c = 0; c < 4; c++) acc[c] = (f32x4_t){0.f, 0.f, 0.f, 0.f};

    for (int k0 = 0; k0 < 256; k0 += 64) {
        const float4* ag = (const float4*)(x  + (rowBase + r) * 256 + k0 + cs);
        const float4* bg = (const float4*)(Wt + (long)(colBase + r) * 256 + k0 + cs);
        float4 av[4], bv[4];
#pragma unroll
        for (int q = 0; q < 4; q++) { av[q] = ag[q]; bv[q] = bg[q]; }

        __align__(16) __hip_bfloat16 ta[16], tb[16];
#pragma unroll
        for (int q = 0; q < 4; q++) {
            ta[q * 4 + 0] = __float2bfloat16(av[q].x);
            ta[q * 4 + 1] = __float2bfloat16(av[q].y);
            ta[q * 4 + 2] = __float2bfloat16(av[q].z);
            ta[q * 4 + 3] = __float2bfloat16(av[q].w);
            tb[q * 4 + 0] = __float2bfloat16(bv[q].x);
            tb[q * 4 + 1] = __float2bfloat16(bv[q].y);
            tb[q * 4 + 2] = __float2bfloat16(bv[q].z);
            tb[q * 4 + 3] = __float2bfloat16(bv[q].w);
        }

        __syncthreads();
        *(uint4*)&As[r][cs]     = *(uint4*)&ta[0];
        *(uint4*)&As[r][cs + 8] = *(uint4*)&ta[8];
        *(uint4*)&Bs[r][cs]     = *(uint4*)&tb[0];
        *(uint4*)&Bs[r][cs + 8] = *(uint4*)&tb[8];
        __syncthreads();

#pragma unroll
        for (int kk = 0; kk < 64; kk += 32) {
            bf16x8_t af = *(const bf16x8_t*)&As[w * 16 + m16][kk + quad * 8];
#pragma unroll
            for (int c = 0; c < 4; c++) {
                bf16x8_t bf = *(const bf16x8_t*)&Bs[c * 16 + m16][kk + quad * 8];
                acc[c] = __builtin_amdgcn_mfma_f32_16x16x32_bf16(af, bf, acc[c], 0, 0, 0);
            }
        }
    }

    // Epilogue: C/D layout col = lane&15 (N side), row = quad*4 + reg (M side)
#pragma unroll
    for (int c = 0; c < 4; c++) {
        const int col = colBase + c * 16 + m16;
        const float bv = bias[col];
#pragma unroll
        for (int reg = 0; reg < 4; reg++) {
            const long row = rowBase + w * 16 + quad * 4 + reg;
            h[row * 256 + col] = __float2bfloat16(acc[c][reg] + bv);
        }
    }
}

// ---------------------------------------------------------------------------
// Kernel B: s1 = h@a1, s2 = h@a2 per row (fp32). One wave per row.
// ---------------------------------------------------------------------------
struct __attribute__((aligned(8))) bf4 { __hip_bfloat16 v[4]; };

__global__ __launch_bounds__(256) void s_kernel(
    const __hip_bfloat16* __restrict__ h,
    const float* __restrict__ a1,
    const float* __restrict__ a2,
    float* __restrict__ s1, float* __restrict__ s2)
{
    const int w = threadIdx.x >> 6;
    const int lane = threadIdx.x & 63;
    const long row = (long)blockIdx.x * 4 + w;

    bf4 hv = *(const bf4*)(h + row * 256 + lane * 4);
    float4 A1 = *(const float4*)(a1 + lane * 4);
    float4 A2 = *(const float4*)(a2 + lane * 4);
    const float h0 = __bfloat162float(hv.v[0]), h1 = __bfloat162float(hv.v[1]);
    const float h2 = __bfloat162float(hv.v[2]), h3 = __bfloat162float(hv.v[3]);
    float p1 = h0 * A1.x + h1 * A1.y + h2 * A1.z + h3 * A1.w;
    float p2 = h0 * A2.x + h1 * A2.y + h2 * A2.z + h3 * A2.w;
#pragma unroll
    for (int off = 32; off; off >>= 1) {
        p1 += __shfl_down(p1, off);
        p2 += __shfl_down(p2, off);
    }
    if (lane == 0) { s1[row] = p1; s2[row] = p2; }
}

// ---------------------------------------------------------------------------
// Kernel C: sparse attention aggregate. One block per (b,i) row, 256 threads,
// thread = output channel (round-2 shape: max blocks, max waves in flight).
// Scan compacts nonzero edges via wave-ballot (8 LDS atomics/wave, j-sorted
// per segment); gather loops the compact list with 8 loads in flight,
// using precomputed byte offsets (j<<9) + SGPR-base addressing.
// b = blockIdx & 7 -> batch<->XCD affinity keeps 1 MB h slice hot in L2.
// ---------------------------------------------------------------------------
__global__ __launch_bounds__(256) void attn_agg(
    const float* __restrict__ adj,
    const float* __restrict__ mask,
    const __hip_bfloat16* __restrict__ h,
    const float* __restrict__ s1,
    const float* __restrict__ s2,
    const float* __restrict__ attb_p,
    float* __restrict__ out)
{
    __shared__ int   s_off[2048];   // byte offset j*512 into this batch's h slice
    __shared__ float s_w[2048];
    __shared__ int   s_cnt;
    __shared__ float s_red[4];
    __shared__ float s_inv;

    const int tid = threadIdx.x;
    const int b   = blockIdx.x & 7;
    const int i   = blockIdx.x >> 3;
    const long row = (long)b * NN + i;
    const long mbase = (long)b * NN;

    const float mask_i = mask[row];
    if (mask_i == 0.f) {                      // block-uniform branch; no barrier yet
        out[row * 256 + tid] = 0.f;
        return;
    }
    if (tid == 0) s_cnt = 0;
    __syncthreads();

    const float si = s1[row] + attb_p[0];
    const int lane = tid & 63;
    const int wv   = tid >> 6;

    // ---- scan: 2048 adj entries, 8 per thread (two coalesced float4 loads) ----
    const float4* arow = (const float4*)(adj + row * NN);
    float4 A0 = arow[tid * 2];
    float4 A1 = arow[tid * 2 + 1];
    float av[8] = {A0.x, A0.y, A0.z, A0.w, A1.x, A1.y, A1.z, A1.w};
    float lsum = 0.f;
#pragma unroll
    for (int e = 0; e < 8; e++) {
        const int j = tid * 8 + e;
        bool pred = (av[e] != 0.f);
        float wgt = 0.f;
        if (pred) {
            const float mj = mask[mbase + j];
            if (mj != 0.f) {
                const float z = si + s2[mbase + j];
                wgt = av[e] * mj / (1.f + __expf(-z));
            } else {
                pred = false;
            }
        }
        // wave-ballot compaction: one LDS atomic per wave per e
        const unsigned long long bm = __ballot(pred);
        int base = 0;
        if (lane == 0) base = atomicAdd(&s_cnt, (int)__popcll(bm));
        base = __shfl(base, 0);
        if (pred) {
            const int pos = base + (int)__popcll(bm & ((1ull << lane) - 1ull));
            s_off[pos] = j << 9;      // j * 512 bytes (256 bf16 per h row)
            s_w[pos]   = wgt;
            lsum += wgt;
        }
    }

    // ---- denominator: wave shuffle-reduce + cross-wave via LDS ----
#pragma unroll
    for (int off = 32; off; off >>= 1) lsum += __shfl_down(lsum, off);
    if (lane == 0) s_red[wv] = lsum;
    __syncthreads();
    if (tid == 0)
        s_inv = 1.f / (s_red[0] + s_red[1] + s_red[2] + s_red[3] + 1e-8f);
    __syncthreads();

    // ---- gather: thread owns channel d = tid; 8 loads in flight ----
    const int cnt  = s_cnt;
    const float inv = s_inv;
    const char* hb = (const char*)(h + mbase * 256);   // block-uniform -> SGPR base
    const int toff = tid * 2;
    float acc = 0.f;
    int k = 0;
    for (; k + 8 <= cnt; k += 8) {
        int o[8]; float w[8];
#pragma unroll
        for (int q = 0; q < 8; q++) { o[q] = s_off[k + q]; w[q] = s_w[k + q]; }
        float g[8];
#pragma unroll
        for (int q = 0; q < 8; q++) {
            const unsigned short u = *(const unsigned short*)(hb + (o[q] + toff));
            g[q] = __uint_as_float(((unsigned)u) << 16);
        }
#pragma unroll
        for (int q = 0; q < 8; q++) acc += w[q] * g[q];
    }
    for (; k < cnt; k++) {
        const unsigned short u = *(const unsigned short*)(hb + (s_off[k] + toff));
        acc += s_w[k] * __uint_as_float(((unsigned)u) << 16);
    }

    out[row * 256 + tid] = acc * inv;   // cnt==0 -> 0
}

// ---------------------------------------------------------------------------
extern "C" void kernel_launch(void* const* d_in, const int* in_sizes, int n_in,
                              void* d_out, int out_size, void* d_ws, size_t ws_size,
                              hipStream_t stream) {
    const float* x    = (const float*)d_in[0];
    const float* adj  = (const float*)d_in[1];
    const float* mask = (const float*)d_in[2];
    const float* W    = (const float*)d_in[3];
    const float* bias = (const float*)d_in[4];
    const float* a1   = (const float*)d_in[5];
    const float* a2   = (const float*)d_in[6];
    const float* attb = (const float*)d_in[7];
    float* out = (float*)d_out;

    // workspace layout: h bf16 [16384*256] (8 MB) | s1 fp32 [16384] | s2 fp32 [16384]
    __hip_bfloat16* h = (__hip_bfloat16*)d_ws;
    float* s1 = (float*)((char*)d_ws + (size_t)MM * DD * 2);
    float* s2 = s1 + MM;

    gemm_h<<<dim3(MM / 64, DD / 64), 256, 0, stream>>>(x, W, bias, h);
    s_kernel<<<MM / 4, 256, 0, stream>>>(h, a1, a2, s1, s2);
    attn_agg<<<MM, 256, 0, stream>>>(adj, mask, h, s1, s2, attb, out);
}

// Round 5
// 238.492 us; speedup vs baseline: 1.2391x; 1.1175x over previous
//
#include <hip/hip_runtime.h>
#include <hip/hip_bf16.h>

// Problem dims (fixed by reference)
#define BB 8
#define NN 2048
#define DD 256
#define MM (BB * NN)   // 16384 rows

typedef __attribute__((ext_vector_type(8))) short bf16x8_t;  // 8 bf16 = 4 VGPRs
typedef __attribute__((ext_vector_type(4))) float f32x4_t;

// ---------------------------------------------------------------------------
// Kernel A: h = x @ W^T + b. fp32 inputs, converted to bf16 at LDS staging,
// bf16 MFMA w/ fp32 accumulate, h written as bf16 (workspace).
// grid (M/64, 256/64), block 256 (4 waves).
// ---------------------------------------------------------------------------
__global__ __launch_bounds__(256) void gemm_h(
    const float* __restrict__ x,     // [M,256] fp32
    const float* __restrict__ Wt,    // [256,256] fp32 row-major [out,in] (B^T form)
    const float* __restrict__ bias,  // [256] fp32
    __hip_bfloat16* __restrict__ h)  // [M,256] bf16
{
    __shared__ __hip_bfloat16 As[64][72];
    __shared__ __hip_bfloat16 Bs[64][72];

    const int tid  = threadIdx.x;
    const int r    = tid >> 2;          // 0..63 staging row
    const int cs   = (tid & 3) * 16;    // k-segment 0/16/32/48
    const int w    = tid >> 6;          // wave 0..3
    const int lane = tid & 63;
    const int m16  = lane & 15;
    const int quad = lane >> 4;
    const long rowBase = (long)blockIdx.x * 64;
    const int  colBase = blockIdx.y * 64;

    f32x4_t acc[4];
#pragma unroll
    for (int c = 0; c < 4; c++) acc[c] = (f32x4_t){0.f, 0.f, 0.f, 0.f};

    for (int k0 = 0; k0 < 256; k0 += 64) {
        const float4* ag = (const float4*)(x  + (rowBase + r) * 256 + k0 + cs);
        const float4* bg = (const float4*)(Wt + (long)(colBase + r) * 256 + k0 + cs);
        float4 av[4], bv[4];
#pragma unroll
        for (int q = 0; q < 4; q++) { av[q] = ag[q]; bv[q] = bg[q]; }

        __align__(16) __hip_bfloat16 ta[16], tb[16];
#pragma unroll
        for (int q = 0; q < 4; q++) {
            ta[q * 4 + 0] = __float2bfloat16(av[q].x);
            ta[q * 4 + 1] = __float2bfloat16(av[q].y);
            ta[q * 4 + 2] = __float2bfloat16(av[q].z);
            ta[q * 4 + 3] = __float2bfloat16(av[q].w);
            tb[q * 4 + 0] = __float2bfloat16(bv[q].x);
            tb[q * 4 + 1] = __float2bfloat16(bv[q].y);
            tb[q * 4 + 2] = __float2bfloat16(bv[q].z);
            tb[q * 4 + 3] = __float2bfloat16(bv[q].w);
        }

        __syncthreads();
        *(uint4*)&As[r][cs]     = *(uint4*)&ta[0];
        *(uint4*)&As[r][cs + 8] = *(uint4*)&ta[8];
        *(uint4*)&Bs[r][cs]     = *(uint4*)&tb[0];
        *(uint4*)&Bs[r][cs + 8] = *(uint4*)&tb[8];
        __syncthreads();

#pragma unroll
        for (int kk = 0; kk < 64; kk += 32) {
            bf16x8_t af = *(const bf16x8_t*)&As[w * 16 + m16][kk + quad * 8];
#pragma unroll
            for (int c = 0; c < 4; c++) {
                bf16x8_t bf = *(const bf16x8_t*)&Bs[c * 16 + m16][kk + quad * 8];
                acc[c] = __builtin_amdgcn_mfma_f32_16x16x32_bf16(af, bf, acc[c], 0, 0, 0);
            }
        }
    }

    // Epilogue: C/D layout col = lane&15 (N side), row = quad*4 + reg (M side)
#pragma unroll
    for (int c = 0; c < 4; c++) {
        const int col = colBase + c * 16 + m16;
        const float bv = bias[col];
#pragma unroll
        for (int reg = 0; reg < 4; reg++) {
            const long row = rowBase + w * 16 + quad * 4 + reg;
            h[row * 256 + col] = __float2bfloat16(acc[c][reg] + bv);
        }
    }
}

// ---------------------------------------------------------------------------
// Kernel B: per row: s1b = h@a1 + att_b ; t2 = mask ? h@a2 : -1e30.
// One wave per row. t2 folds the j-side mask so attn_agg's scan is branchless:
// sigmoid(si + (-1e30)) == rcp(+inf) == 0 exactly -> masked edges drop out.
// ---------------------------------------------------------------------------
struct __attribute__((aligned(8))) bf4 { __hip_bfloat16 v[4]; };

__global__ __launch_bounds__(256) void s_kernel(
    const __hip_bfloat16* __restrict__ h,
    const float* __restrict__ a1,
    const float* __restrict__ a2,
    const float* __restrict__ mask,
    const float* __restrict__ attb_p,
    float* __restrict__ s1b, float* __restrict__ t2)
{
    const int w = threadIdx.x >> 6;
    const int lane = threadIdx.x & 63;
    const long row = (long)blockIdx.x * 4 + w;

    bf4 hv = *(const bf4*)(h + row * 256 + lane * 4);
    float4 A1 = *(const float4*)(a1 + lane * 4);
    float4 A2 = *(const float4*)(a2 + lane * 4);
    const float h0 = __bfloat162float(hv.v[0]), h1 = __bfloat162float(hv.v[1]);
    const float h2 = __bfloat162float(hv.v[2]), h3 = __bfloat162float(hv.v[3]);
    float p1 = h0 * A1.x + h1 * A1.y + h2 * A1.z + h3 * A1.w;
    float p2 = h0 * A2.x + h1 * A2.y + h2 * A2.z + h3 * A2.w;
#pragma unroll
    for (int off = 32; off; off >>= 1) {
        p1 += __shfl_down(p1, off);
        p2 += __shfl_down(p2, off);
    }
    if (lane == 0) {
        s1b[row] = p1 + attb_p[0];
        t2[row]  = (mask[row] != 0.f) ? p2 : -1e30f;
    }
}

// ---------------------------------------------------------------------------
// Kernel C: sparse attention aggregate. One block per (b,i) row, 256 threads.
// Scan: fully-coalesced unconditional float4 adj+t2 reads, branchless sigmoid
// (v_exp + v_rcp), divergent append only (R2-proven cheap LDS atomic).
// Gather: dword loads (2 channels/thread, t = tid&127), neighbor list split
// into contiguous halves between the two 128-thread groups, 8 loads in
// flight, pre-shifted byte offsets. List reads are wave-uniform -> broadcast.
// b = blockIdx & 7 keeps each batch's 1 MB h slice hot in one XCD's L2.
// ---------------------------------------------------------------------------
__global__ __launch_bounds__(256) void attn_agg(
    const float* __restrict__ adj,
    const float* __restrict__ mask,
    const __hip_bfloat16* __restrict__ h,
    const float* __restrict__ s1b,
    const float* __restrict__ t2,
    float* __restrict__ out)
{
    __shared__ float2 s_list[1024];   // .x = byte offset (j<<9) as int bits, .y = weight
    __shared__ int    s_cnt;
    __shared__ float  s_red[4];
    __shared__ float  s_inv;
    __shared__ float2 s_part[128];

    const int tid = threadIdx.x;
    const int b   = blockIdx.x & 7;
    const int i   = blockIdx.x >> 3;
    const long row   = (long)b * NN + i;
    const long mbase = (long)b * NN;

    const float mask_i = mask[row];
    if (mask_i == 0.f) {                  // block-uniform early exit (no barriers yet)
        out[row * 256 + tid] = 0.f;
        return;
    }
    if (tid == 0) s_cnt = 0;
    __syncthreads();

    const float si = s1b[row];
    const float4* arow = (const float4*)(adj + row * NN);
    const float4* trow = (const float4*)(t2 + mbase);

    float4 A0 = arow[tid], A1 = arow[256 + tid];   // coalesced: j = tid*4.. / 1024+tid*4..
    float4 T0 = trow[tid], T1 = trow[256 + tid];   // L1-resident (64 KB array)

    float lsum = 0.f;
#pragma unroll
    for (int g = 0; g < 2; g++) {
        const int jb = g * 1024 + tid * 4;
        const float av[4] = {g ? A1.x : A0.x, g ? A1.y : A0.y, g ? A1.z : A0.z, g ? A1.w : A0.w};
        const float tv[4] = {g ? T1.x : T0.x, g ? T1.y : T0.y, g ? T1.z : T0.z, g ? T1.w : T0.w};
#pragma unroll
        for (int e = 0; e < 4; e++) {
            const float z   = si + tv[e];
            const float sig = __builtin_amdgcn_rcpf(1.f + __expf(-z));  // rcp(inf)=0 for masked j
            const float wgt = av[e] * sig;
            lsum += wgt;
            if (wgt != 0.f) {             // exec-masked append, ~1 active lane/wave-iter
                const int pos = atomicAdd(&s_cnt, 1);
                if (pos < 1024)
                    s_list[pos] = make_float2(__int_as_float((jb + e) << 9), wgt);
            }
        }
    }

    // ---- denominator: wave shuffle-reduce + cross-wave via LDS ----
#pragma unroll
    for (int off = 32; off; off >>= 1) lsum += __shfl_down(lsum, off);
    const int lane = tid & 63, wv = tid >> 6;
    if (lane == 0) s_red[wv] = lsum;
    __syncthreads();
    if (tid == 0)
        s_inv = 1.f / (s_red[0] + s_red[1] + s_red[2] + s_red[3] + 1e-8f);
    __syncthreads();

    // ---- gather: group g takes a contiguous half of the list; thread owns
    //      channel pair {2t, 2t+1} via one dword load per neighbor ----
    const int cnt  = min(s_cnt, 1024);
    const float inv = s_inv * mask_i;     // mask_i==1 for valid rows (binary mask)
    const char* hb = (const char*)(h + mbase * 256);   // block-uniform -> SGPR base
    const int g  = tid >> 7;
    const int t  = tid & 127;
    const int t4 = t * 4;
    const int half = (cnt + 1) >> 1;
    int k       = g ? half : 0;
    const int end = g ? cnt : half;

    float accx = 0.f, accy = 0.f;
    for (; k + 8 <= end; k += 8) {
        float2 e[8];
#pragma unroll
        for (int q = 0; q < 8; q++) e[q] = s_list[k + q];      // wave-uniform: broadcast
        unsigned u[8];
#pragma unroll
        for (int q = 0; q < 8; q++)
            u[q] = *(const unsigned*)(hb + (__float_as_int(e[q].x) + t4));
#pragma unroll
        for (int q = 0; q < 8; q++) {
            accx += e[q].y * __uint_as_float(u[q] << 16);
            accy += e[q].y * __uint_as_float(u[q] & 0xffff0000u);
        }
    }
    for (; k + 4 <= end; k += 4) {
        float2 e[4];
#pragma unroll
        for (int q = 0; q < 4; q++) e[q] = s_list[k + q];
        unsigned u[4];
#pragma unroll
        for (int q = 0; q < 4; q++)
            u[q] = *(const unsigned*)(hb + (__float_as_int(e[q].x) + t4));
#pragma unroll
        for (int q = 0; q < 4; q++) {
            accx += e[q].y * __uint_as_float(u[q] << 16);
            accy += e[q].y * __uint_as_float(u[q] & 0xffff0000u);
        }
    }
    for (; k < end; k++) {
        float2 ee = s_list[k];
        unsigned u = *(const unsigned*)(hb + (__float_as_int(ee.x) + t4));
        accx += ee.y * __uint_as_float(u << 16);
        accy += ee.y * __uint_as_float(u & 0xffff0000u);
    }

    // combine the two groups' partial sums, group 0 writes float2
    if (g) s_part[t] = make_float2(accx, accy);
    __syncthreads();
    if (!g) {
        const float2 p = s_part[t];
        ((float2*)(out + row * 256))[t] =
            make_float2((accx + p.x) * inv, (accy + p.y) * inv);
    }
}

// ---------------------------------------------------------------------------
extern "C" void kernel_launch(void* const* d_in, const int* in_sizes, int n_in,
                              void* d_out, int out_size, void* d_ws, size_t ws_size,
                              hipStream_t stream) {
    const float* x    = (const float*)d_in[0];
    const float* adj  = (const float*)d_in[1];
    const float* mask = (const float*)d_in[2];
    const float* W    = (const float*)d_in[3];
    const float* bias = (const float*)d_in[4];
    const float* a1   = (const float*)d_in[5];
    const float* a2   = (const float*)d_in[6];
    const float* attb = (const float*)d_in[7];
    float* out = (float*)d_out;

    // workspace: h bf16 [16384*256] (8 MB) | s1b fp32 [16384] | t2 fp32 [16384]
    __hip_bfloat16* h = (__hip_bfloat16*)d_ws;
    float* s1b = (float*)((char*)d_ws + (size_t)MM * DD * 2);
    float* t2  = s1b + MM;

    gemm_h<<<dim3(MM / 64, DD / 64), 256, 0, stream>>>(x, W, bias, h);
    s_kernel<<<MM / 4, 256, 0, stream>>>(h, a1, a2, mask, attb, s1b, t2);
    attn_agg<<<MM, 256, 0, stream>>>(adj, mask, h, s1b, t2, out);
}